// Round 2
// baseline (4920.494 us; speedup 1.0000x reference)
//
#include <hip/hip_runtime.h>
#include <math.h>

// CILRS fused head. B=65536 rows; fp32 in/out/compute.
// Round 1: correctness baseline — 1 row per 256-thread block, fully fused,
// LDS intermediates. Only the selected branch (command-1) is computed
// (reference computes all 6 densely then masks; identical result).

#define B_ 65536
#define D_ 512
#define H_ 256
#define NB_ 6

__global__ __launch_bounds__(256) void cilrs_fused(
    const float* __restrict__ embedding,  // [B,D]
    const float* __restrict__ speed,      // [B]
    const int*   __restrict__ command,    // [B] values 1..6
    const float* __restrict__ sw1,        // [1,H]
    const float* __restrict__ sb1,        // [H]
    const float* __restrict__ sw2,        // [H,D]
    const float* __restrict__ sb2,        // [D]
    const float* __restrict__ bw1,        // [NB,D,H]
    const float* __restrict__ bb1,        // [NB,H]
    const float* __restrict__ bw2,        // [NB,H,H]
    const float* __restrict__ bb2,        // [NB,H]
    const float* __restrict__ bw3,        // [NB,H,3]
    const float* __restrict__ bb3,        // [NB,3]
    const float* __restrict__ ow1,        // [D,H]
    const float* __restrict__ ob1,        // [H]
    const float* __restrict__ ow2,        // [H,H]
    const float* __restrict__ ob2,        // [H]
    const float* __restrict__ ow3,        // [H,1]
    const float* __restrict__ ob3,        // [1]
    float* __restrict__ out)              // [B*3] control ++ [B] speed
{
    const int row = blockIdx.x;
    const int j   = threadIdx.x;   // 0..255

    __shared__ float sh[H_];    // speed hidden, later reused as t1
    __shared__ float emb[D_];
    __shared__ float h1[H_];    // branch hidden 1, later reused as t2
    __shared__ float h2[H_];    // branch hidden 2

    // ---- speed_in layer 1: sh = relu(speed * sw1 + sb1) ----
    const float spd = speed[row];
    {
        float v = spd * sw1[j] + sb1[j];
        sh[j] = v > 0.f ? v : 0.f;
    }
    __syncthreads();

    // ---- emb = embedding + sh @ sw2 + sb2  (thread j owns cols j, j+256) ----
    {
        float acc0 = 0.f, acc1 = 0.f;
        #pragma unroll 8
        for (int h = 0; h < H_; ++h) {
            const float s = sh[h];
            acc0 += s * sw2[h * D_ + j];
            acc1 += s * sw2[h * D_ + j + 256];
        }
        emb[j]       = embedding[(size_t)row * D_ + j]       + acc0 + sb2[j];
        emb[j + 256] = embedding[(size_t)row * D_ + j + 256] + acc1 + sb2[j + 256];
    }
    __syncthreads();

    const int n = command[row] - 1;   // 0..5

    // ---- branch layer 1: h1 = relu(emb @ bw1[n] + bb1[n]) ----
    {
        const float* w = bw1 + (size_t)n * D_ * H_;
        float acc = 0.f;
        #pragma unroll 8
        for (int d = 0; d < D_; ++d) acc += emb[d] * w[d * H_ + j];
        acc += bb1[n * H_ + j];
        h1[j] = acc > 0.f ? acc : 0.f;
    }
    __syncthreads();

    // ---- branch layer 2: h2 = relu(h1 @ bw2[n] + bb2[n]) ----
    {
        const float* w = bw2 + (size_t)n * H_ * H_;
        float acc = 0.f;
        #pragma unroll 8
        for (int h = 0; h < H_; ++h) acc += h1[h] * w[h * H_ + j];
        acc += bb2[n * H_ + j];
        h2[j] = acc > 0.f ? acc : 0.f;
    }
    __syncthreads();

    // ---- speed_out layer 1: t1 = relu(emb @ ow1 + ob1)  (reuse sh) ----
    {
        float acc = 0.f;
        #pragma unroll 8
        for (int d = 0; d < D_; ++d) acc += emb[d] * ow1[d * H_ + j];
        acc += ob1[j];
        sh[j] = acc > 0.f ? acc : 0.f;   // t1
    }
    __syncthreads();

    // ---- speed_out layer 2: t2 = relu(t1 @ ow2 + ob2)  (reuse h1) ----
    {
        float acc = 0.f;
        #pragma unroll 8
        for (int h = 0; h < H_; ++h) acc += sh[h] * ow2[h * H_ + j];
        acc += ob2[j];
        h1[j] = acc > 0.f ? acc : 0.f;   // t2
    }
    __syncthreads();

    // ---- heads: threads 0..2 -> control (sigmoid), thread 3 -> speed ----
    if (j < 3) {
        const float* w = bw3 + (size_t)n * H_ * 3;
        float acc = 0.f;
        #pragma unroll 8
        for (int h = 0; h < H_; ++h) acc += h2[h] * w[h * 3 + j];
        acc += bb3[n * 3 + j];
        const float sig = 1.f / (1.f + expf(-acc));
        out[(size_t)row * 3 + j] = sig;
    } else if (j == 3) {
        float acc = 0.f;
        #pragma unroll 8
        for (int h = 0; h < H_; ++h) acc += h1[h] * ow3[h];
        acc += ob3[0];
        out[(size_t)B_ * 3 + row] = acc;
    }
}

extern "C" void kernel_launch(void* const* d_in, const int* in_sizes, int n_in,
                              void* d_out, int out_size, void* d_ws, size_t ws_size,
                              hipStream_t stream) {
    const float* embedding = (const float*)d_in[0];
    const float* speed     = (const float*)d_in[1];
    const int*   command   = (const int*)  d_in[2];
    const float* sw1 = (const float*)d_in[3];
    const float* sb1 = (const float*)d_in[4];
    const float* sw2 = (const float*)d_in[5];
    const float* sb2 = (const float*)d_in[6];
    const float* bw1 = (const float*)d_in[7];
    const float* bb1 = (const float*)d_in[8];
    const float* bw2 = (const float*)d_in[9];
    const float* bb2 = (const float*)d_in[10];
    const float* bw3 = (const float*)d_in[11];
    const float* bb3 = (const float*)d_in[12];
    const float* ow1 = (const float*)d_in[13];
    const float* ob1 = (const float*)d_in[14];
    const float* ow2 = (const float*)d_in[15];
    const float* ob2 = (const float*)d_in[16];
    const float* ow3 = (const float*)d_in[17];
    const float* ob3 = (const float*)d_in[18];
    float* out = (float*)d_out;

    cilrs_fused<<<B_, 256, 0, stream>>>(embedding, speed, command,
                                        sw1, sb1, sw2, sb2,
                                        bw1, bb1, bw2, bb2, bw3, bb3,
                                        ow1, ob1, ow2, ob2, ow3, ob3,
                                        out);
}

// Round 3
// 1380.869 us; speedup vs baseline: 3.5633x; 3.5633x over previous
//
#include <hip/hip_runtime.h>
#include <math.h>

// CILRS fused head, MFMA version.
// Round 2: bucket rows by command (device-side), pre-transpose+bf16 weights
// into ws, then one fused bf16-MFMA kernel: each wave owns 16 rows through
// the whole layer chain. Fallback to the fp32 round-1 kernel if ws is small.

#define B_ 65536
#define D_ 512
#define H_ 256
#define NB_ 6

typedef float  f32x4  __attribute__((ext_vector_type(4)));
typedef __bf16 bf16x8 __attribute__((ext_vector_type(8)));

// ---- ws layout (bytes) ----
#define OFF_COUNTS   0          // 8 ints (+8 cursors at 32)
#define OFF_CURSORS  32
#define OFF_PERM     256        // 65536 ints = 262144 B
#define OFF_SW2T     262400     // [512][256] bf16  (sw2T[d][h] = sw2[h][d])
#define OFF_BW1T     524544     // [6][256][512] bf16
#define OFF_BW2T     2097408    // [6][256][256] bf16
#define OFF_OW1T     2883840    // [256][512] bf16
#define OFF_OW2T     3145984    // [256][256] bf16
#define WS_NEEDED    3277056

// ---------------- prep kernels ----------------

__global__ void k_zero(int* counts) {
    if (threadIdx.x < 16) counts[threadIdx.x] = 0;   // counts[8] + cursors[8]
}

__global__ void k_count(const int* __restrict__ command, int* __restrict__ counts) {
    int i = blockIdx.x * 256 + threadIdx.x;
    int c = command[i] - 1; c = min(max(c, 0), 5);
    atomicAdd(&counts[c], 1);
}

__global__ void k_scan(const int* __restrict__ counts, int* __restrict__ cursors) {
    if (threadIdx.x == 0) {
        int s = 0;
        for (int c = 0; c < 6; ++c) { cursors[c] = s; s += counts[c]; }
    }
}

__global__ void k_scatter(const int* __restrict__ command, int* __restrict__ cursors,
                          int* __restrict__ perm) {
    int i = blockIdx.x * 256 + threadIdx.x;
    int c = command[i] - 1; c = min(max(c, 0), 5);
    int pos = atomicAdd(&cursors[c], 1);
    perm[pos] = i;
}

// W: [C][K][N] fp32 row-major  ->  WT: [C][N][K] bf16
template<int K, int N>
__global__ void k_transpose(const float* __restrict__ W, __bf16* __restrict__ WT, int total) {
    int t = blockIdx.x * 256 + threadIdx.x;
    if (t >= total) return;
    int c   = t / (K * N);
    int rem = t - c * (K * N);
    int n   = rem / K;
    int k   = rem - n * K;
    WT[t] = (__bf16)W[(size_t)c * (K * N) + (size_t)k * N + n];
}

// ---------------- fused MFMA kernel ----------------
// A-fragment (16x16x32 bf16): lane holds A[m][k], m=lane&15, k=(lane>>4)*8+j
// B-fragment:                 lane holds B[k][n], n=lane&15, k=(lane>>4)*8+j
// C/D:                        col=lane&15, row=(lane>>4)*4+reg

template<int NT, int KSTEPS>
__device__ inline void gemm_tile(const __bf16* aBase, int apitch,
                                 const __bf16* bBase, int bpitch,
                                 int lane, f32x4* acc)
{
    const int am = lane & 15;
    const int kg = (lane >> 4) * 8;
    #pragma unroll 2
    for (int ks = 0; ks < KSTEPS; ++ks) {
        bf16x8 a = *(const bf16x8*)(aBase + am * apitch + ks * 32 + kg);
        #pragma unroll
        for (int ct = 0; ct < NT; ++ct) {
            bf16x8 b = *(const bf16x8*)(bBase + (size_t)(ct * 16 + am) * bpitch + ks * 32 + kg);
            acc[ct] = __builtin_amdgcn_mfma_f32_16x16x32_bf16(a, b, acc[ct], 0, 0, 0);
        }
    }
}

__global__ __launch_bounds__(128) void cilrs_mfma(
    const float* __restrict__ embedding, const float* __restrict__ speed,
    const int*   __restrict__ command,
    const float* __restrict__ sw1, const float* __restrict__ sb1,
    const float* __restrict__ sb2,
    const float* __restrict__ bb1, const float* __restrict__ bb2,
    const float* __restrict__ bw3, const float* __restrict__ bb3,
    const float* __restrict__ ob1, const float* __restrict__ ob2,
    const float* __restrict__ ow3, const float* __restrict__ ob3,
    const int*   __restrict__ perm,
    const __bf16* __restrict__ sw2T, const __bf16* __restrict__ bw1T,
    const __bf16* __restrict__ bw2T, const __bf16* __restrict__ ow1T,
    const __bf16* __restrict__ ow2T,
    float* __restrict__ out)
{
    // per-wave private buffers (wave w uses only its own slice; pitches padded
    // so A-fragment ds_read_b128 is at most 2-way bank aliased)
    __shared__ __align__(16) __bf16 s_emb[2][16][520];   // emb tile, bf16
    __shared__ __align__(16) __bf16 s_scr[2][16][264];   // sh -> h1 -> t1
    __shared__ int   s_ridx[2][16];
    __shared__ int   s_cmd[2][16];
    __shared__ float s_spd[2][16];

    const int w    = threadIdx.x >> 6;
    const int lane = threadIdx.x & 63;
    const int rowBase = blockIdx.x * 32 + w * 16;

    if (lane < 16) {
        int r = perm[rowBase + lane];
        s_ridx[w][lane] = r;
        int c = command[r] - 1; c = min(max(c, 0), 5);
        s_cmd[w][lane] = c;
        s_spd[w][lane] = speed[r];
    }
    __syncthreads();

    int cmin = 5, cmax = 0;
    #pragma unroll
    for (int i = 0; i < 16; ++i) { int c = s_cmd[w][i]; cmin = min(cmin, c); cmax = max(cmax, c); }

    const int lrow0 = (lane >> 4) * 4;   // C/D row base for this lane
    const int lcol  = lane & 15;         // C/D col within tile
    int rr[4], cc[4];
    #pragma unroll
    for (int g = 0; g < 4; ++g) { rr[g] = s_ridx[w][lrow0 + g]; cc[g] = s_cmd[w][lrow0 + g]; }

    // ---- build sh tile: sh[r][h] = relu(speed[r]*sw1[h] + sb1[h]) ----
    {
        float swv[4], sbv[4];
        #pragma unroll
        for (int jj = 0; jj < 4; ++jj) { int h = lane + 64 * jj; swv[jj] = sw1[h]; sbv[jj] = sb1[h]; }
        #pragma unroll 4
        for (int r = 0; r < 16; ++r) {
            float sp = s_spd[w][r];
            #pragma unroll
            for (int jj = 0; jj < 4; ++jj) {
                float v = fmaxf(sp * swv[jj] + sbv[jj], 0.f);
                s_scr[w][r][lane + 64 * jj] = (__bf16)v;
            }
        }
    }
    __syncthreads();

    // ---- L1: emb = embedding + sh @ sw2 + sb2   (two 256-col halves) ----
    #pragma unroll
    for (int half = 0; half < 2; ++half) {
        f32x4 acc[16];
        #pragma unroll
        for (int i = 0; i < 16; ++i) acc[i] = f32x4{0.f, 0.f, 0.f, 0.f};
        gemm_tile<16, 8>(&s_scr[w][0][0], 264, sw2T + (size_t)(half * 256) * 256, 256, lane, acc);
        #pragma unroll
        for (int ct = 0; ct < 16; ++ct) {
            int col = half * 256 + ct * 16 + lcol;
            float sbv = sb2[col];
            #pragma unroll
            for (int g = 0; g < 4; ++g) {
                float v = acc[ct][g] + sbv + embedding[(size_t)rr[g] * D_ + col];
                s_emb[w][lrow0 + g][col] = (__bf16)v;
            }
        }
    }
    __syncthreads();

    // ---- L2: h1 = relu(emb @ bw1[c] + bb1[c]), masked store per row ----
    for (int c = cmin; c <= cmax; ++c) {
        f32x4 acc[16];
        #pragma unroll
        for (int i = 0; i < 16; ++i) acc[i] = f32x4{0.f, 0.f, 0.f, 0.f};
        gemm_tile<16, 16>(&s_emb[w][0][0], 520, bw1T + (size_t)c * 256 * 512, 512, lane, acc);
        #pragma unroll
        for (int ct = 0; ct < 16; ++ct) {
            int col = ct * 16 + lcol;
            float bb = bb1[c * H_ + col];
            #pragma unroll
            for (int g = 0; g < 4; ++g) {
                if (cc[g] == c) {
                    float v = fmaxf(acc[ct][g] + bb, 0.f);
                    s_scr[w][lrow0 + g][col] = (__bf16)v;
                }
            }
        }
    }
    __syncthreads();

    // ---- L3: h2 = relu(h1 @ bw2[c] + bb2[c]); control head in-register ----
    for (int c = cmin; c <= cmax; ++c) {
        f32x4 acc[16];
        #pragma unroll
        for (int i = 0; i < 16; ++i) acc[i] = f32x4{0.f, 0.f, 0.f, 0.f};
        gemm_tile<16, 8>(&s_scr[w][0][0], 264, bw2T + (size_t)c * 256 * 256, 256, lane, acc);
        float cp[4][3] = {};
        #pragma unroll
        for (int ct = 0; ct < 16; ++ct) {
            int col = ct * 16 + lcol;
            float bb = bb2[c * H_ + col];
            float w0 = bw3[(c * H_ + col) * 3 + 0];
            float w1 = bw3[(c * H_ + col) * 3 + 1];
            float w2 = bw3[(c * H_ + col) * 3 + 2];
            #pragma unroll
            for (int g = 0; g < 4; ++g) {
                float h = fmaxf(acc[ct][g] + bb, 0.f);
                cp[g][0] += h * w0; cp[g][1] += h * w1; cp[g][2] += h * w2;
            }
        }
        #pragma unroll
        for (int g = 0; g < 4; ++g)
            #pragma unroll
            for (int o = 0; o < 3; ++o) {
                cp[g][o] += __shfl_xor(cp[g][o], 1);
                cp[g][o] += __shfl_xor(cp[g][o], 2);
                cp[g][o] += __shfl_xor(cp[g][o], 4);
                cp[g][o] += __shfl_xor(cp[g][o], 8);
            }
        if (lcol == 0) {
            #pragma unroll
            for (int g = 0; g < 4; ++g) if (cc[g] == c) {
                #pragma unroll
                for (int o = 0; o < 3; ++o) {
                    float x = cp[g][o] + bb3[c * 3 + o];
                    out[(size_t)rr[g] * 3 + o] = 1.f / (1.f + __expf(-x));
                }
            }
        }
    }
    __syncthreads();

    // ---- L4: t1 = relu(emb @ ow1 + ob1) -> s_scr (all rows) ----
    {
        f32x4 acc[16];
        #pragma unroll
        for (int i = 0; i < 16; ++i) acc[i] = f32x4{0.f, 0.f, 0.f, 0.f};
        gemm_tile<16, 16>(&s_emb[w][0][0], 520, ow1T, 512, lane, acc);
        #pragma unroll
        for (int ct = 0; ct < 16; ++ct) {
            int col = ct * 16 + lcol;
            float bb = ob1[col];
            #pragma unroll
            for (int g = 0; g < 4; ++g) {
                float v = fmaxf(acc[ct][g] + bb, 0.f);
                s_scr[w][lrow0 + g][col] = (__bf16)v;
            }
        }
    }
    __syncthreads();

    // ---- L5: t2 = relu(t1 @ ow2 + ob2); speed head in-register ----
    {
        f32x4 acc[16];
        #pragma unroll
        for (int i = 0; i < 16; ++i) acc[i] = f32x4{0.f, 0.f, 0.f, 0.f};
        gemm_tile<16, 8>(&s_scr[w][0][0], 264, ow2T, 256, lane, acc);
        float sp[4] = {0.f, 0.f, 0.f, 0.f};
        #pragma unroll
        for (int ct = 0; ct < 16; ++ct) {
            int col = ct * 16 + lcol;
            float bb = ob2[col];
            float wv = ow3[col];
            #pragma unroll
            for (int g = 0; g < 4; ++g) {
                float t = fmaxf(acc[ct][g] + bb, 0.f);
                sp[g] += t * wv;
            }
        }
        #pragma unroll
        for (int g = 0; g < 4; ++g) {
            sp[g] += __shfl_xor(sp[g], 1);
            sp[g] += __shfl_xor(sp[g], 2);
            sp[g] += __shfl_xor(sp[g], 4);
            sp[g] += __shfl_xor(sp[g], 8);
        }
        if (lcol == 0) {
            #pragma unroll
            for (int g = 0; g < 4; ++g)
                out[(size_t)3 * B_ + rr[g]] = sp[g] + ob3[0];
        }
    }
}

// ---------------- fallback (round-1 fp32 kernel) ----------------

__global__ __launch_bounds__(256) void cilrs_slow(
    const float* __restrict__ embedding, const float* __restrict__ speed,
    const int* __restrict__ command,
    const float* __restrict__ sw1, const float* __restrict__ sb1,
    const float* __restrict__ sw2, const float* __restrict__ sb2,
    const float* __restrict__ bw1, const float* __restrict__ bb1,
    const float* __restrict__ bw2, const float* __restrict__ bb2,
    const float* __restrict__ bw3, const float* __restrict__ bb3,
    const float* __restrict__ ow1, const float* __restrict__ ob1,
    const float* __restrict__ ow2, const float* __restrict__ ob2,
    const float* __restrict__ ow3, const float* __restrict__ ob3,
    float* __restrict__ out)
{
    const int row = blockIdx.x;
    const int j   = threadIdx.x;
    __shared__ float sh[H_];
    __shared__ float emb[D_];
    __shared__ float h1[H_];
    __shared__ float h2[H_];
    const float spd = speed[row];
    { float v = spd * sw1[j] + sb1[j]; sh[j] = v > 0.f ? v : 0.f; }
    __syncthreads();
    {
        float acc0 = 0.f, acc1 = 0.f;
        for (int h = 0; h < H_; ++h) {
            const float s = sh[h];
            acc0 += s * sw2[h * D_ + j];
            acc1 += s * sw2[h * D_ + j + 256];
        }
        emb[j]       = embedding[(size_t)row * D_ + j]       + acc0 + sb2[j];
        emb[j + 256] = embedding[(size_t)row * D_ + j + 256] + acc1 + sb2[j + 256];
    }
    __syncthreads();
    const int n = command[row] - 1;
    {
        const float* wp = bw1 + (size_t)n * D_ * H_;
        float acc = 0.f;
        for (int d = 0; d < D_; ++d) acc += emb[d] * wp[d * H_ + j];
        acc += bb1[n * H_ + j];
        h1[j] = acc > 0.f ? acc : 0.f;
    }
    __syncthreads();
    {
        const float* wp = bw2 + (size_t)n * H_ * H_;
        float acc = 0.f;
        for (int h = 0; h < H_; ++h) acc += h1[h] * wp[h * H_ + j];
        acc += bb2[n * H_ + j];
        h2[j] = acc > 0.f ? acc : 0.f;
    }
    __syncthreads();
    {
        float acc = 0.f;
        for (int d = 0; d < D_; ++d) acc += emb[d] * ow1[d * H_ + j];
        acc += ob1[j];
        sh[j] = acc > 0.f ? acc : 0.f;
    }
    __syncthreads();
    {
        float acc = 0.f;
        for (int h = 0; h < H_; ++h) acc += sh[h] * ow2[h * H_ + j];
        acc += ob2[j];
        h1[j] = acc > 0.f ? acc : 0.f;
    }
    __syncthreads();
    if (j < 3) {
        const float* wp = bw3 + (size_t)n * H_ * 3;
        float acc = 0.f;
        for (int h = 0; h < H_; ++h) acc += h2[h] * wp[h * 3 + j];
        acc += bb3[n * 3 + j];
        out[(size_t)row * 3 + j] = 1.f / (1.f + expf(-acc));
    } else if (j == 3) {
        float acc = 0.f;
        for (int h = 0; h < H_; ++h) acc += h1[h] * ow3[h];
        acc += ob3[0];
        out[(size_t)B_ * 3 + row] = acc;
    }
}

// ---------------- launch ----------------

extern "C" void kernel_launch(void* const* d_in, const int* in_sizes, int n_in,
                              void* d_out, int out_size, void* d_ws, size_t ws_size,
                              hipStream_t stream) {
    const float* embedding = (const float*)d_in[0];
    const float* speed     = (const float*)d_in[1];
    const int*   command   = (const int*)  d_in[2];
    const float* sw1 = (const float*)d_in[3];
    const float* sb1 = (const float*)d_in[4];
    const float* sw2 = (const float*)d_in[5];
    const float* sb2 = (const float*)d_in[6];
    const float* bw1 = (const float*)d_in[7];
    const float* bb1 = (const float*)d_in[8];
    const float* bw2 = (const float*)d_in[9];
    const float* bb2 = (const float*)d_in[10];
    const float* bw3 = (const float*)d_in[11];
    const float* bb3 = (const float*)d_in[12];
    const float* ow1 = (const float*)d_in[13];
    const float* ob1 = (const float*)d_in[14];
    const float* ow2 = (const float*)d_in[15];
    const float* ob2 = (const float*)d_in[16];
    const float* ow3 = (const float*)d_in[17];
    const float* ob3 = (const float*)d_in[18];
    float* out = (float*)d_out;

    if (ws_size < (size_t)WS_NEEDED) {
        cilrs_slow<<<B_, 256, 0, stream>>>(embedding, speed, command,
                                           sw1, sb1, sw2, sb2,
                                           bw1, bb1, bw2, bb2, bw3, bb3,
                                           ow1, ob1, ow2, ob2, ow3, ob3, out);
        return;
    }

    char* ws = (char*)d_ws;
    int*    counts  = (int*)   (ws + OFF_COUNTS);
    int*    cursors = (int*)   (ws + OFF_CURSORS);
    int*    perm    = (int*)   (ws + OFF_PERM);
    __bf16* sw2T    = (__bf16*)(ws + OFF_SW2T);
    __bf16* bw1T    = (__bf16*)(ws + OFF_BW1T);
    __bf16* bw2T    = (__bf16*)(ws + OFF_BW2T);
    __bf16* ow1T    = (__bf16*)(ws + OFF_OW1T);
    __bf16* ow2T    = (__bf16*)(ws + OFF_OW2T);

    k_zero<<<1, 64, 0, stream>>>(counts);
    k_count<<<B_ / 256, 256, 0, stream>>>(command, counts);
    k_scan<<<1, 64, 0, stream>>>(counts, cursors);
    k_scatter<<<B_ / 256, 256, 0, stream>>>(command, cursors, perm);

    k_transpose<256, 512><<< (1 * 256 * 512) / 256, 256, 0, stream>>>(sw2, sw2T, 1 * 256 * 512);
    k_transpose<512, 256><<< (6 * 512 * 256) / 256, 256, 0, stream>>>(bw1, bw1T, 6 * 512 * 256);
    k_transpose<256, 256><<< (6 * 256 * 256) / 256, 256, 0, stream>>>(bw2, bw2T, 6 * 256 * 256);
    k_transpose<512, 256><<< (1 * 512 * 256) / 256, 256, 0, stream>>>(ow1, ow1T, 1 * 512 * 256);
    k_transpose<256, 256><<< (1 * 256 * 256) / 256, 256, 0, stream>>>(ow2, ow2T, 1 * 256 * 256);

    cilrs_mfma<<<B_ / 32, 128, 0, stream>>>(embedding, speed, command,
                                            sw1, sb1, sb2,
                                            bb1, bb2, bw3, bb3,
                                            ob1, ob2, ow3, ob3,
                                            perm, sw2T, bw1T, bw2T, ow1T, ow2T,
                                            out);
}

// Round 4
// 497.995 us; speedup vs baseline: 9.8806x; 2.7729x over previous
//
#include <hip/hip_runtime.h>
#include <math.h>

// CILRS fused head — round 4.
// Prep: LDS-histogram bucketing by command + one coalesced pack kernel that
// converts all GEMM weights to bf16 in B-fragment-linear layout [kc][n][32k].
// Main: 384-thread blocks, 96 rows/block (3 row-groups x 2 col-halves);
// each wave: 32 rows x 128 cols via 16x16x32 bf16 MFMA; A from LDS
// activations, B coalesced from packed L2-resident weights; heads via
// in-register dot + shuffle reduce + LDS atomics.

#define B_ 65536
#define D_ 512
#define H_ 256

typedef float  f32x4  __attribute__((ext_vector_type(4)));
typedef __bf16 bf16x8 __attribute__((ext_vector_type(8)));

// ---- ws layout (bytes) ----
#define OFF_COUNTS   0
#define OFF_CURSORS  32
#define OFF_PERM     256        // 65536 ints
#define OFF_PACK     262400     // packed bf16 weights
#define WS_NEEDED    3277056

// packed element offsets (bf16 elements, relative to PK)
#define PKO_SW2   0u         // 2 slices x 65536  (sw2 cols 0-255, 256-511)
#define PKO_BW1   131072u    // 6 x 131072
#define PKO_BW2   917504u    // 6 x 65536
#define PKO_OW1   1310720u   // 131072
#define PKO_OW2   1441792u   // 65536

#define PITCH_E 520   // emb LDS pitch (bf16): 16B-aligned rows, 2-way banks (free)
#define PITCH_A 264   // act LDS pitch

// ---------------- prep kernels ----------------

__global__ void k_zero(int* counts) {
    if (threadIdx.x < 16) counts[threadIdx.x] = 0;
}

__global__ __launch_bounds__(1024) void k_count(const int* __restrict__ command,
                                                int* __restrict__ counts) {
    __shared__ int lh[6];
    int t = threadIdx.x;
    if (t < 6) lh[t] = 0;
    __syncthreads();
    int c = command[blockIdx.x * 1024 + t] - 1; c = min(max(c, 0), 5);
    atomicAdd(&lh[c], 1);
    __syncthreads();
    if (t < 6) atomicAdd(&counts[t], lh[t]);
}

__global__ void k_scan(const int* __restrict__ counts, int* __restrict__ cursors) {
    if (threadIdx.x == 0) {
        int s = 0;
        for (int c = 0; c < 6; ++c) { cursors[c] = s; s += counts[c]; }
    }
}

__global__ __launch_bounds__(1024) void k_scatter(const int* __restrict__ command,
                                                  int* __restrict__ cursors,
                                                  int* __restrict__ perm) {
    __shared__ int lh[6], lbase[6];
    int t = threadIdx.x;
    if (t < 6) lh[t] = 0;
    __syncthreads();
    int i = blockIdx.x * 1024 + t;
    int c = command[i] - 1; c = min(max(c, 0), 5);
    int rank = atomicAdd(&lh[c], 1);
    __syncthreads();
    if (t < 6) lbase[t] = atomicAdd(&cursors[t], lh[t]);
    __syncthreads();
    perm[lbase[c] + rank] = i;
}

// One kernel packs ALL weights: fp32 [K][srcN] (col slice) -> bf16 [kc][n][32].
// Tile = 32k x 64n per block. Reads coalesced along n; writes coalesced 16B.
__global__ __launch_bounds__(256) void k_pack(const float* __restrict__ sw2,
                                              const float* __restrict__ bw1,
                                              const float* __restrict__ bw2,
                                              const float* __restrict__ ow1,
                                              const float* __restrict__ ow2,
                                              __bf16* __restrict__ PK) {
    int b = blockIdx.x;
    const float* src; int srcN, colOff; unsigned dstOff; int tt;
    if (b < 64)       { int s = b >> 5;        tt = b & 31;  src = sw2;                          srcN = 512; colOff = s * 256; dstOff = PKO_SW2 + s * 65536u; }
    else if (b < 448) { int i = b - 64;  int c = i >> 6; tt = i & 63; src = bw1 + (size_t)c * 512 * 256; srcN = 256; colOff = 0; dstOff = PKO_BW1 + c * 131072u; }
    else if (b < 640) { int i = b - 448; int c = i >> 5; tt = i & 31; src = bw2 + (size_t)c * 256 * 256; srcN = 256; colOff = 0; dstOff = PKO_BW2 + c * 65536u; }
    else if (b < 704) { tt = b - 640; src = ow1; srcN = 256; colOff = 0; dstOff = PKO_OW1; }
    else              { tt = b - 704; src = ow2; srcN = 256; colOff = 0; dstOff = PKO_OW2; }
    int kc = tt >> 2, nt = tt & 3;
    int k0 = kc * 32, n0 = nt * 64;

    __shared__ __bf16 T[64][34];
    int t = threadIdx.x;
    #pragma unroll
    for (int p = 0; p < 8; ++p) {
        int idx = p * 256 + t;
        int k = idx >> 6, n = idx & 63;
        T[n][k] = (__bf16)src[(size_t)(k0 + k) * srcN + colOff + n0 + n];
    }
    __syncthreads();
    int n = t >> 2, seg = t & 3;
    bf16x8 v;
    #pragma unroll
    for (int j = 0; j < 8; ++j) v[j] = T[n][seg * 8 + j];
    *(bf16x8*)(PK + dstOff + ((unsigned)(kc * 256 + n0 + n) * 32u + seg * 8u)) = v;
}

// ---------------- main fused kernel ----------------
// A-frag 16x16x32: lane holds A[m=lane&15][k=(lane>>4)*8+j]
// B-frag:          lane holds B[k=(lane>>4)*8+j][n=lane&15]
// C/D:             col=lane&15, row=(lane>>4)*4+reg

template<int NKS>
__device__ __forceinline__ void gemm2x8(const __bf16* __restrict__ a0,
                                        const __bf16* __restrict__ a1,
                                        const __bf16* __restrict__ bp,
                                        f32x4 acc[2][8]) {
    #pragma unroll 2
    for (int ks = 0; ks < NKS; ++ks) {
        bf16x8 av0 = *(const bf16x8*)(a0 + ks * 32);
        bf16x8 av1 = *(const bf16x8*)(a1 + ks * 32);
        #pragma unroll
        for (int ct = 0; ct < 8; ++ct) {
            bf16x8 bv = *(const bf16x8*)(bp + (size_t)ks * 8192 + ct * 512);
            acc[0][ct] = __builtin_amdgcn_mfma_f32_16x16x32_bf16(av0, bv, acc[0][ct], 0, 0, 0);
            acc[1][ct] = __builtin_amdgcn_mfma_f32_16x16x32_bf16(av1, bv, acc[1][ct], 0, 0, 0);
        }
    }
}

__global__ __launch_bounds__(384, 1) void cilrs_main(
    const float* __restrict__ embedding, const float* __restrict__ speed,
    const int*   __restrict__ command,
    const float* __restrict__ sw1, const float* __restrict__ sb1,
    const float* __restrict__ sb2,
    const float* __restrict__ bb1, const float* __restrict__ bb2,
    const float* __restrict__ bw3, const float* __restrict__ bb3,
    const float* __restrict__ ob1, const float* __restrict__ ob2,
    const float* __restrict__ ow3, const float* __restrict__ ob3,
    const int*   __restrict__ perm, const __bf16* __restrict__ PK,
    float* __restrict__ out)
{
    __shared__ __bf16 s_emb[96 * PITCH_E];
    __shared__ __bf16 s_act[96 * PITCH_A];
    __shared__ float  s_head[96][4];
    __shared__ int    s_row[96];
    __shared__ int    s_cmdA[96];
    __shared__ float  s_spd[96];

    const int tid  = threadIdx.x;
    const int wave = tid >> 6, lane = tid & 63;
    const int g3 = wave >> 1, ch = wave & 1;   // row-group 0..2, col-half 0..1
    const int lm = lane & 15, kg = lane >> 4;
    const int lrow0 = kg * 4;
    const int R0 = blockIdx.x * 96;

    if (tid < 96) {
        int gr = R0 + tid; if (gr > B_ - 1) gr = B_ - 1;   // tail block: benign dup rows
        int ridx = perm[gr];
        s_row[tid] = ridx;
        int c = command[ridx] - 1; c = min(max(c, 0), 5);
        s_cmdA[tid] = c;
        s_spd[tid] = speed[ridx];
        s_head[tid][0] = 0.f; s_head[tid][1] = 0.f; s_head[tid][2] = 0.f; s_head[tid][3] = 0.f;
    }
    __syncthreads();

    // per-lane row indices / commands for this wave's 32 rows (C-layout rows)
    int rr[2][4], cc[2][4];
    #pragma unroll
    for (int mt = 0; mt < 2; ++mt)
        #pragma unroll
        for (int g = 0; g < 4; ++g) {
            int row = g3 * 32 + mt * 16 + lrow0 + g;
            rr[mt][g] = s_row[row];
            cc[mt][g] = s_cmdA[row];
        }

    // wave-wide branch range over its 32 rows
    int myc = s_cmdA[g3 * 32 + (lane & 31)];
    int cmin = myc, cmax = myc;
    #pragma unroll
    for (int d = 1; d < 32; d <<= 1) {
        cmin = min(cmin, __shfl_xor(cmin, d));
        cmax = max(cmax, __shfl_xor(cmax, d));
    }

    // ---- sh tile: act[row][h] = relu(speed*sw1[h]+sb1[h]) ----
    {
        int h0 = ch * 128 + lane, h1 = ch * 128 + 64 + lane;
        float w0 = sw1[h0], b0 = sb1[h0], w1 = sw1[h1], b1 = sb1[h1];
        #pragma unroll 4
        for (int r = 0; r < 32; ++r) {
            int row = g3 * 32 + r;
            float sp = s_spd[row];
            s_act[row * PITCH_A + h0] = (__bf16)fmaxf(sp * w0 + b0, 0.f);
            s_act[row * PITCH_A + h1] = (__bf16)fmaxf(sp * w1 + b1, 0.f);
        }
    }
    __syncthreads();

    const __bf16* aA0 = s_act + (g3 * 32 + lm) * PITCH_A + kg * 8;
    const __bf16* aA1 = s_act + (g3 * 32 + 16 + lm) * PITCH_A + kg * 8;
    const __bf16* aE0 = s_emb + (g3 * 32 + lm) * PITCH_E + kg * 8;
    const __bf16* aE1 = s_emb + (g3 * 32 + 16 + lm) * PITCH_E + kg * 8;
    const size_t bcol = (size_t)(ch * 128 + lm) * 32 + kg * 8;

    // ---- L1: emb = embedding + sh @ sw2 + sb2  (two 256-col passes) ----
    #pragma unroll 1
    for (int p = 0; p < 2; ++p) {
        f32x4 acc[2][8];
        #pragma unroll
        for (int mt = 0; mt < 2; ++mt)
            #pragma unroll
            for (int ct = 0; ct < 8; ++ct) acc[mt][ct] = f32x4{0.f, 0.f, 0.f, 0.f};
        gemm2x8<8>(aA0, aA1, PK + PKO_SW2 + p * 65536u + bcol, acc);
        #pragma unroll
        for (int ct = 0; ct < 8; ++ct) {
            int col = p * 256 + ch * 128 + ct * 16 + lm;
            float sb = sb2[col];
            #pragma unroll
            for (int mt = 0; mt < 2; ++mt)
                #pragma unroll
                for (int g = 0; g < 4; ++g) {
                    int row = g3 * 32 + mt * 16 + lrow0 + g;
                    float v = acc[mt][ct][g] + sb + embedding[(size_t)rr[mt][g] * D_ + col];
                    s_emb[row * PITCH_E + col] = (__bf16)v;
                }
        }
    }
    __syncthreads();

    // ---- L2: h1 = relu(emb @ bw1[c] + bb1[c]) -> act (masked per row) ----
    for (int c = cmin; c <= cmax; ++c) {
        f32x4 acc[2][8];
        #pragma unroll
        for (int mt = 0; mt < 2; ++mt)
            #pragma unroll
            for (int ct = 0; ct < 8; ++ct) acc[mt][ct] = f32x4{0.f, 0.f, 0.f, 0.f};
        gemm2x8<16>(aE0, aE1, PK + PKO_BW1 + c * 131072u + bcol, acc);
        #pragma unroll
        for (int ct = 0; ct < 8; ++ct) {
            int col = ch * 128 + ct * 16 + lm;
            float b = bb1[c * H_ + col];
            #pragma unroll
            for (int mt = 0; mt < 2; ++mt)
                #pragma unroll
                for (int g = 0; g < 4; ++g)
                    if (cc[mt][g] == c) {
                        int row = g3 * 32 + mt * 16 + lrow0 + g;
                        s_act[row * PITCH_A + col] = (__bf16)fmaxf(acc[mt][ct][g] + b, 0.f);
                    }
        }
    }
    __syncthreads();

    // ---- L3: h2 = relu(h1 @ bw2[c] + bb2[c]); control head in-register ----
    for (int c = cmin; c <= cmax; ++c) {
        f32x4 acc[2][8];
        #pragma unroll
        for (int mt = 0; mt < 2; ++mt)
            #pragma unroll
            for (int ct = 0; ct < 8; ++ct) acc[mt][ct] = f32x4{0.f, 0.f, 0.f, 0.f};
        gemm2x8<8>(aA0, aA1, PK + PKO_BW2 + c * 65536u + bcol, acc);
        float ph[2][4][3];
        #pragma unroll
        for (int mt = 0; mt < 2; ++mt)
            #pragma unroll
            for (int g = 0; g < 4; ++g) { ph[mt][g][0] = 0.f; ph[mt][g][1] = 0.f; ph[mt][g][2] = 0.f; }
        #pragma unroll
        for (int ct = 0; ct < 8; ++ct) {
            int col = ch * 128 + ct * 16 + lm;
            float b  = bb2[c * H_ + col];
            float w0 = bw3[(c * H_ + col) * 3 + 0];
            float w1 = bw3[(c * H_ + col) * 3 + 1];
            float w2 = bw3[(c * H_ + col) * 3 + 2];
            #pragma unroll
            for (int mt = 0; mt < 2; ++mt)
                #pragma unroll
                for (int g = 0; g < 4; ++g) {
                    float h = fmaxf(acc[mt][ct][g] + b, 0.f);
                    ph[mt][g][0] += h * w0; ph[mt][g][1] += h * w1; ph[mt][g][2] += h * w2;
                }
        }
        #pragma unroll
        for (int mt = 0; mt < 2; ++mt)
            #pragma unroll
            for (int g = 0; g < 4; ++g)
                #pragma unroll
                for (int o = 0; o < 3; ++o) {
                    float v = ph[mt][g][o];
                    v += __shfl_xor(v, 1); v += __shfl_xor(v, 2);
                    v += __shfl_xor(v, 4); v += __shfl_xor(v, 8);
                    ph[mt][g][o] = v;
                }
        if (lm == 0) {
            #pragma unroll
            for (int mt = 0; mt < 2; ++mt)
                #pragma unroll
                for (int g = 0; g < 4; ++g)
                    if (cc[mt][g] == c) {
                        int row = g3 * 32 + mt * 16 + lrow0 + g;
                        atomicAdd(&s_head[row][0], ph[mt][g][0]);
                        atomicAdd(&s_head[row][1], ph[mt][g][1]);
                        atomicAdd(&s_head[row][2], ph[mt][g][2]);
                    }
        }
    }
    __syncthreads();

    // ---- L4: t1 = relu(emb @ ow1 + ob1) -> act (all rows) ----
    {
        f32x4 acc[2][8];
        #pragma unroll
        for (int mt = 0; mt < 2; ++mt)
            #pragma unroll
            for (int ct = 0; ct < 8; ++ct) acc[mt][ct] = f32x4{0.f, 0.f, 0.f, 0.f};
        gemm2x8<16>(aE0, aE1, PK + PKO_OW1 + bcol, acc);
        #pragma unroll
        for (int ct = 0; ct < 8; ++ct) {
            int col = ch * 128 + ct * 16 + lm;
            float b = ob1[col];
            #pragma unroll
            for (int mt = 0; mt < 2; ++mt)
                #pragma unroll
                for (int g = 0; g < 4; ++g) {
                    int row = g3 * 32 + mt * 16 + lrow0 + g;
                    s_act[row * PITCH_A + col] = (__bf16)fmaxf(acc[mt][ct][g] + b, 0.f);
                }
        }
    }
    __syncthreads();

    // ---- L5: t2 = relu(t1 @ ow2 + ob2); speed head in-register ----
    {
        f32x4 acc[2][8];
        #pragma unroll
        for (int mt = 0; mt < 2; ++mt)
            #pragma unroll
            for (int ct = 0; ct < 8; ++ct) acc[mt][ct] = f32x4{0.f, 0.f, 0.f, 0.f};
        gemm2x8<8>(aA0, aA1, PK + PKO_OW2 + bcol, acc);
        float sp[2][4];
        #pragma unroll
        for (int mt = 0; mt < 2; ++mt)
            #pragma unroll
            for (int g = 0; g < 4; ++g) sp[mt][g] = 0.f;
        #pragma unroll
        for (int ct = 0; ct < 8; ++ct) {
            int col = ch * 128 + ct * 16 + lm;
            float b = ob2[col], wv = ow3[col];
            #pragma unroll
            for (int mt = 0; mt < 2; ++mt)
                #pragma unroll
                for (int g = 0; g < 4; ++g)
                    sp[mt][g] += fmaxf(acc[mt][ct][g] + b, 0.f) * wv;
        }
        #pragma unroll
        for (int mt = 0; mt < 2; ++mt)
            #pragma unroll
            for (int g = 0; g < 4; ++g) {
                float v = sp[mt][g];
                v += __shfl_xor(v, 1); v += __shfl_xor(v, 2);
                v += __shfl_xor(v, 4); v += __shfl_xor(v, 8);
                if (lm == 0) {
                    int row = g3 * 32 + mt * 16 + lrow0 + g;
                    atomicAdd(&s_head[row][3], v);
                }
            }
    }
    __syncthreads();

    // ---- final store ----
    if (tid < 96) {
        int ridx = s_row[tid], c = s_cmdA[tid];
        #pragma unroll
        for (int o = 0; o < 3; ++o) {
            float x = s_head[tid][o] + bb3[c * 3 + o];
            out[(size_t)ridx * 3 + o] = 1.f / (1.f + __expf(-x));
        }
        out[(size_t)3 * B_ + ridx] = s_head[tid][3] + ob3[0];
    }
}

// ---------------- fallback (fp32, no ws) ----------------

__global__ __launch_bounds__(256) void cilrs_slow(
    const float* __restrict__ embedding, const float* __restrict__ speed,
    const int* __restrict__ command,
    const float* __restrict__ sw1, const float* __restrict__ sb1,
    const float* __restrict__ sw2, const float* __restrict__ sb2,
    const float* __restrict__ bw1, const float* __restrict__ bb1,
    const float* __restrict__ bw2, const float* __restrict__ bb2,
    const float* __restrict__ bw3, const float* __restrict__ bb3,
    const float* __restrict__ ow1, const float* __restrict__ ob1,
    const float* __restrict__ ow2, const float* __restrict__ ob2,
    const float* __restrict__ ow3, const float* __restrict__ ob3,
    float* __restrict__ out)
{
    const int row = blockIdx.x;
    const int j   = threadIdx.x;
    __shared__ float sh[H_];
    __shared__ float emb[D_];
    __shared__ float h1[H_];
    __shared__ float h2[H_];
    const float spd = speed[row];
    { float v = spd * sw1[j] + sb1[j]; sh[j] = v > 0.f ? v : 0.f; }
    __syncthreads();
    {
        float a0 = 0.f, a1 = 0.f;
        for (int h = 0; h < H_; ++h) {
            const float s = sh[h];
            a0 += s * sw2[h * D_ + j];
            a1 += s * sw2[h * D_ + j + 256];
        }
        emb[j]       = embedding[(size_t)row * D_ + j]       + a0 + sb2[j];
        emb[j + 256] = embedding[(size_t)row * D_ + j + 256] + a1 + sb2[j + 256];
    }
    __syncthreads();
    const int n = command[row] - 1;
    {
        const float* wp = bw1 + (size_t)n * D_ * H_;
        float a = 0.f;
        for (int d = 0; d < D_; ++d) a += emb[d] * wp[d * H_ + j];
        a += bb1[n * H_ + j];
        h1[j] = a > 0.f ? a : 0.f;
    }
    __syncthreads();
    {
        const float* wp = bw2 + (size_t)n * H_ * H_;
        float a = 0.f;
        for (int h = 0; h < H_; ++h) a += h1[h] * wp[h * H_ + j];
        a += bb2[n * H_ + j];
        h2[j] = a > 0.f ? a : 0.f;
    }
    __syncthreads();
    {
        float a = 0.f;
        for (int d = 0; d < D_; ++d) a += emb[d] * ow1[d * H_ + j];
        a += ob1[j];
        sh[j] = a > 0.f ? a : 0.f;
    }
    __syncthreads();
    {
        float a = 0.f;
        for (int h = 0; h < H_; ++h) a += sh[h] * ow2[h * H_ + j];
        a += ob2[j];
        h1[j] = a > 0.f ? a : 0.f;
    }
    __syncthreads();
    if (j < 3) {
        const float* wp = bw3 + (size_t)n * H_ * 3;
        float a = 0.f;
        for (int h = 0; h < H_; ++h) a += h2[h] * wp[h * 3 + j];
        a += bb3[n * 3 + j];
        out[(size_t)row * 3 + j] = 1.f / (1.f + expf(-a));
    } else if (j == 3) {
        float a = 0.f;
        for (int h = 0; h < H_; ++h) a += h1[h] * ow3[h];
        a += ob3[0];
        out[(size_t)B_ * 3 + row] = a;
    }
}

// ---------------- launch ----------------

extern "C" void kernel_launch(void* const* d_in, const int* in_sizes, int n_in,
                              void* d_out, int out_size, void* d_ws, size_t ws_size,
                              hipStream_t stream) {
    const float* embedding = (const float*)d_in[0];
    const float* speed     = (const float*)d_in[1];
    const int*   command   = (const int*)  d_in[2];
    const float* sw1 = (const float*)d_in[3];
    const float* sb1 = (const float*)d_in[4];
    const float* sw2 = (const float*)d_in[5];
    const float* sb2 = (const float*)d_in[6];
    const float* bw1 = (const float*)d_in[7];
    const float* bb1 = (const float*)d_in[8];
    const float* bw2 = (const float*)d_in[9];
    const float* bb2 = (const float*)d_in[10];
    const float* bw3 = (const float*)d_in[11];
    const float* bb3 = (const float*)d_in[12];
    const float* ow1 = (const float*)d_in[13];
    const float* ob1 = (const float*)d_in[14];
    const float* ow2 = (const float*)d_in[15];
    const float* ob2 = (const float*)d_in[16];
    const float* ow3 = (const float*)d_in[17];
    const float* ob3 = (const float*)d_in[18];
    float* out = (float*)d_out;

    if (ws_size < (size_t)WS_NEEDED) {
        cilrs_slow<<<B_, 256, 0, stream>>>(embedding, speed, command,
                                           sw1, sb1, sw2, sb2,
                                           bw1, bb1, bw2, bb2, bw3, bb3,
                                           ow1, ob1, ow2, ob2, ow3, ob3, out);
        return;
    }

    char* ws = (char*)d_ws;
    int*    counts  = (int*)   (ws + OFF_COUNTS);
    int*    cursors = (int*)   (ws + OFF_CURSORS);
    int*    perm    = (int*)   (ws + OFF_PERM);
    __bf16* PK      = (__bf16*)(ws + OFF_PACK);

    k_zero<<<1, 64, 0, stream>>>(counts);
    k_count<<<B_ / 1024, 1024, 0, stream>>>(command, counts);
    k_scan<<<1, 64, 0, stream>>>(counts, cursors);
    k_scatter<<<B_ / 1024, 1024, 0, stream>>>(command, cursors, perm);
    k_pack<<<736, 256, 0, stream>>>(sw2, bw1, bw2, ow1, ow2, PK);

    cilrs_main<<<(B_ + 95) / 96, 384, 0, stream>>>(embedding, speed, command,
                                                   sw1, sb1, sb2,
                                                   bb1, bb2, bw3, bb3,
                                                   ob1, ob2, ow3, ob3,
                                                   perm, PK, out);
}